// Round 1
// baseline (873.955 us; speedup 1.0000x reference)
//
#include <hip/hip_runtime.h>
#include <hip/hip_bf16.h>

// GCN forward: 5x (agg -> linear -> relu) + segment_max pool + 4-layer MLP head
// + log_softmax. N=100000 nodes, E=1600000 edges, C=32, G=128 graphs.
//
// Structure:
//  - counting sort by dst -> CSR (cnt, offsets, csr_src); deg = cnt + 1 (self loop)
//  - features stored pre-scaled: ht[i] = dinv[i] * h[i]
//  - agg[v][c] = dinv[v] * (ht[v][c] + sum_{e: dst=v} ht[src_e][c])   (atomic-free)
//  - transform: h_next = relu(agg @ W^T + b), stored scaled by dinv except last layer
//  - pool: chunked running-max over sorted batch, flushed via uint atomicMax (h >= 0)
//  - head: one 128-thread block, fully unrolled 32x32 matmuls in registers

#define CDIM 32

__global__ void count_kernel(const int* __restrict__ edst, int* __restrict__ cnt, int E) {
    int e = blockIdx.x * 256 + threadIdx.x;
    if (e < E) atomicAdd(&cnt[edst[e]], 1);
}

__global__ void dinv_kernel(const int* __restrict__ cnt, float* __restrict__ dinv, int N) {
    int i = blockIdx.x * 256 + threadIdx.x;
    if (i < N) dinv[i] = rsqrtf((float)cnt[i] + 1.0f);
}

__global__ void scan_reduce(const int* __restrict__ cnt, int* __restrict__ bsums, int N) {
    __shared__ int s[256];
    int t = threadIdx.x;
    int i = blockIdx.x * 256 + t;
    s[t] = (i < N) ? cnt[i] : 0;
    __syncthreads();
    for (int d = 128; d > 0; d >>= 1) {
        if (t < d) s[t] += s[t + d];
        __syncthreads();
    }
    if (t == 0) bsums[blockIdx.x] = s[0];
}

// single block, 512 threads; nb <= 512 (N=100000 -> nb=391)
__global__ void scan_bsums(int* bsums, int nb) {
    __shared__ int s[512];
    int t = threadIdx.x;
    int v = (t < nb) ? bsums[t] : 0;
    s[t] = v;
    __syncthreads();
    for (int d = 1; d < 512; d <<= 1) {
        int x = (t >= d) ? s[t - d] : 0;
        __syncthreads();
        s[t] += x;
        __syncthreads();
    }
    if (t < nb) bsums[t] = s[t] - v;  // exclusive
}

__global__ void scan_final(const int* __restrict__ cnt, const int* __restrict__ bsums,
                           int* __restrict__ offsets, int* __restrict__ cursor, int N) {
    __shared__ int s[256];
    int t = threadIdx.x;
    int i = blockIdx.x * 256 + t;
    int v = (i < N) ? cnt[i] : 0;
    s[t] = v;
    __syncthreads();
    for (int d = 1; d < 256; d <<= 1) {
        int x = (t >= d) ? s[t - d] : 0;
        __syncthreads();
        s[t] += x;
        __syncthreads();
    }
    if (i < N) {
        int ex = s[t] - v + bsums[blockIdx.x];
        offsets[i] = ex;
        cursor[i] = ex;
    }
}

__global__ void scatter_kernel(const int* __restrict__ esrc, const int* __restrict__ edst,
                               int* __restrict__ cursor, int* __restrict__ csr_src, int E) {
    int e = blockIdx.x * 256 + threadIdx.x;
    if (e >= E) return;
    int d = edst[e];
    int pos = atomicAdd(&cursor[d], 1);
    csr_src[pos] = esrc[e];
}

// h[i][c] = dinv[i] * embed_w[x_idx[i]][c]  (scaled storage)
__global__ void embed_kernel(const int* __restrict__ x_idx, const float* __restrict__ ew,
                             const float* __restrict__ dinv, float* __restrict__ h, int N) {
    int tid = blockIdx.x * 256 + threadIdx.x;
    int i = tid >> 5, c = tid & 31;
    if (i >= N) return;
    h[tid] = dinv[i] * ew[x_idx[i] * CDIM + c];
}

// out[v][c] = dinv[v] * (ht[v][c] + sum_e ht[src_e][c])   -- true (unscaled) agg
__global__ void agg_kernel(const float* __restrict__ ht, const float* __restrict__ dinv,
                           const int* __restrict__ offsets, const int* __restrict__ cnt,
                           const int* __restrict__ csr_src, float* __restrict__ out, int N) {
    int tid = blockIdx.x * 256 + threadIdx.x;
    int v = tid >> 5, c = tid & 31;
    if (v >= N) return;
    float acc = ht[tid];
    int s0 = offsets[v];
    int e1 = s0 + cnt[v];
    for (int e = s0; e < e1; ++e) {
        int s = csr_src[e];
        acc += ht[s * CDIM + c];
    }
    out[tid] = dinv[v] * acc;
}

// h_next[i][c] = relu( sum_k agg[i][k]*W[c][k] + b[c] ) * (dinv[i] if scale)
#define TNODES 64
__global__ void transform_kernel(const float* __restrict__ agg, const float* __restrict__ W,
                                 const float* __restrict__ b, const float* __restrict__ dinv,
                                 float* __restrict__ out, int N) {
    __shared__ float wsT[CDIM * CDIM];  // wsT[k][c] = W[c][k]
    __shared__ float bias[CDIM];
    __shared__ float hs[TNODES * CDIM];
    int t = threadIdx.x;
    for (int i = t; i < CDIM * CDIM; i += 256)
        wsT[(i & 31) * CDIM + (i >> 5)] = W[i];
    if (t < CDIM) bias[t] = b[t];
    int base = blockIdx.x * TNODES;
    for (int i = t; i < TNODES * CDIM; i += 256) {
        int node = base + (i >> 5);
        hs[i] = (node < N) ? agg[node * CDIM + (i & 31)] : 0.f;
    }
    __syncthreads();
    int c = t & 31, isub = t >> 5;
    #pragma unroll
    for (int j = 0; j < 8; ++j) {
        int li = j * 8 + isub;
        int node = base + li;
        if (node >= N) break;
        float acc = bias[c];
        #pragma unroll
        for (int k = 0; k < CDIM; ++k)
            acc += hs[li * CDIM + k] * wsT[k * CDIM + c];
        float r = fmaxf(acc, 0.f);
        if (dinv) r *= dinv[node];
        out[node * CDIM + c] = r;
    }
}

// chunked segment-max over sorted batch; h >= 0 so uint-bit atomicMax is valid
#define PCHUNK 128
__global__ void pool_kernel(const float* __restrict__ h, const int* __restrict__ batch,
                            unsigned* __restrict__ pooled, int N) {
    __shared__ int sb[8 * PCHUNK];
    int t = threadIdx.x;
    int chunk0 = blockIdx.x * 8;
    int sbase = chunk0 * PCHUNK;
    for (int i = t; i < 8 * PCHUNK; i += 256)
        sb[i] = (sbase + i < N) ? batch[sbase + i] : -1;
    __syncthreads();
    int c = t & 31, cs = t >> 5;
    int i0 = (chunk0 + cs) * PCHUNK;
    if (i0 >= N) return;
    int curg = sb[cs * PCHUNK];
    float m = -1.0f;  // sentinel: nothing accumulated (h values are >= 0)
    for (int k = 0; k < PCHUNK; ++k) {
        int i = i0 + k;
        if (i >= N) break;
        int g = sb[cs * PCHUNK + k];
        float v = h[i * CDIM + c];
        if (g != curg) {
            if (m >= 0.f) atomicMax(&pooled[curg * CDIM + c], __float_as_uint(m));
            curg = g;
            m = v;
        } else {
            m = fmaxf(m, v);
        }
    }
    if (m >= 0.f && curg >= 0) atomicMax(&pooled[curg * CDIM + c], __float_as_uint(m));
}

__global__ void head_kernel(const float* __restrict__ pooled,
                            const float* __restrict__ d0_w, const float* __restrict__ d0_b,
                            const float* __restrict__ dense_w, const float* __restrict__ dense_b,
                            const float* __restrict__ fin_w, const float* __restrict__ fin_b,
                            float* __restrict__ out, int G) {
    int g = threadIdx.x;
    if (g >= G) return;
    float x[CDIM], y[CDIM];
    #pragma unroll
    for (int k = 0; k < CDIM; ++k) x[k] = pooled[g * CDIM + k];
    // d0
    #pragma unroll
    for (int c = 0; c < CDIM; ++c) {
        float a = d0_b[c];
        #pragma unroll
        for (int k = 0; k < CDIM; ++k) a += x[k] * d0_w[c * CDIM + k];
        y[c] = fmaxf(a, 0.f);
    }
    #pragma unroll
    for (int k = 0; k < CDIM; ++k) x[k] = y[k];
    // 3 dense layers
    for (int l = 0; l < 3; ++l) {
        const float* Wl = dense_w + l * CDIM * CDIM;
        const float* bl = dense_b + l * CDIM;
        #pragma unroll
        for (int c = 0; c < CDIM; ++c) {
            float a = bl[c];
            #pragma unroll
            for (int k = 0; k < CDIM; ++k) a += x[k] * Wl[c * CDIM + k];
            y[c] = fmaxf(a, 0.f);
        }
        #pragma unroll
        for (int k = 0; k < CDIM; ++k) x[k] = y[k];
    }
    float l0 = fin_b[0], l1 = fin_b[1];
    #pragma unroll
    for (int k = 0; k < CDIM; ++k) {
        l0 += x[k] * fin_w[k];
        l1 += x[k] * fin_w[CDIM + k];
    }
    float mm = fmaxf(l0, l1);
    float lse = mm + logf(expf(l0 - mm) + expf(l1 - mm));
    out[g * 2 + 0] = l0 - lse;
    out[g * 2 + 1] = l1 - lse;
}

extern "C" void kernel_launch(void* const* d_in, const int* in_sizes, int n_in,
                              void* d_out, int out_size, void* d_ws, size_t ws_size,
                              hipStream_t stream) {
    const int* x_idx = (const int*)d_in[0];
    const int* eidx = (const int*)d_in[1];
    const int* batch = (const int*)d_in[2];
    const float* embed_w = (const float*)d_in[3];
    const float* conv_w = (const float*)d_in[4];
    const float* conv_b = (const float*)d_in[5];
    const float* d0_w = (const float*)d_in[6];
    const float* d0_b = (const float*)d_in[7];
    const float* dense_w = (const float*)d_in[8];
    const float* dense_b = (const float*)d_in[9];
    const float* fin_w = (const float*)d_in[10];
    const float* fin_b = (const float*)d_in[11];

    int N = in_sizes[0];
    int E = in_sizes[1] / 2;
    int G = out_size / 2;
    const int* esrc = eidx;
    const int* edst = eidx + E;

    char* ws = (char*)d_ws;
    size_t off = 0;
    auto take = [&](size_t bytes) -> char* {
        char* p = ws + off;
        off = (off + bytes + 255) & ~(size_t)255;
        return p;
    };
    int* cnt = (int*)take((size_t)N * 4);
    float* dinv = (float*)take((size_t)N * 4);
    int* offsets = (int*)take((size_t)N * 4);
    int* cursor = (int*)take((size_t)N * 4);
    int* bsums = (int*)take(4096 * 4);
    int* csr_src = (int*)take((size_t)E * 4);
    float* hA = (float*)take((size_t)N * CDIM * 4);
    float* hB = (float*)take((size_t)N * CDIM * 4);
    unsigned* pooled = (unsigned*)take((size_t)G * CDIM * 4);
    (void)ws_size;
    (void)n_in;

    hipMemsetAsync(cnt, 0, (size_t)N * 4, stream);
    hipMemsetAsync(pooled, 0, (size_t)G * CDIM * 4, stream);

    int EB = (E + 255) / 256;
    int NB = (N + 255) / 256;
    int NC = (N * CDIM + 255) / 256;

    count_kernel<<<EB, 256, 0, stream>>>(edst, cnt, E);
    dinv_kernel<<<NB, 256, 0, stream>>>(cnt, dinv, N);
    scan_reduce<<<NB, 256, 0, stream>>>(cnt, bsums, N);
    scan_bsums<<<1, 512, 0, stream>>>(bsums, NB);
    scan_final<<<NB, 256, 0, stream>>>(cnt, bsums, offsets, cursor, N);
    scatter_kernel<<<EB, 256, 0, stream>>>(esrc, edst, cursor, csr_src, E);

    embed_kernel<<<NC, 256, 0, stream>>>(x_idx, embed_w, dinv, hA, N);

    for (int l = 0; l < 5; ++l) {
        agg_kernel<<<NC, 256, 0, stream>>>(hA, dinv, offsets, cnt, csr_src, hB, N);
        const float* dscale = (l < 4) ? dinv : nullptr;
        transform_kernel<<<(N + TNODES - 1) / TNODES, 256, 0, stream>>>(
            hB, conv_w + l * CDIM * CDIM, conv_b + l * CDIM, dscale, hA, N);
    }

    int nchunks = (N + PCHUNK - 1) / PCHUNK;
    pool_kernel<<<(nchunks + 7) / 8, 256, 0, stream>>>(hA, batch, pooled, N);
    head_kernel<<<1, 128, 0, stream>>>((const float*)pooled, d0_w, d0_b,
                                       dense_w, dense_b, fin_w, fin_b,
                                       (float*)d_out, G);
}

// Round 2
// 783.964 us; speedup vs baseline: 1.1148x; 1.1148x over previous
//
#include <hip/hip_runtime.h>
#include <hip/hip_bf16.h>

// GCN forward: 5x (agg + linear + relu fused) + segment_max pool + MLP head.
// N=100000, E=1600000, C=32, G=128.
//
//  - counting sort by dst -> CSR (cnt, offsets, csr_src); deg = cnt + 1 (self loop)
//  - features stored pre-scaled: ht[i] = dinv[i] * h[i]
//  - fused layer kernel: 32-lane group per node; CSR gather-accumulate, then
//    in-register 32x32 matmul via __shfl broadcasts (weight row per lane),
//    relu, optional dinv pre-scale for the next layer. No intermediate agg buffer.
//  - layer 1 gathers dinv[s]*embed_w[x_idx[s]] directly (2KB L1-resident table).
//  - pool: chunked running-max over sorted batch, flushed via uint atomicMax
//  - head: one 128-thread block, fully unrolled 32x32 matmuls in registers

#define CDIM 32

__global__ void count_kernel(const int* __restrict__ edst, int* __restrict__ cnt, int E) {
    int e = blockIdx.x * 256 + threadIdx.x;
    if (e < E) atomicAdd(&cnt[edst[e]], 1);
}

__global__ void dinv_kernel(const int* __restrict__ cnt, float* __restrict__ dinv, int N) {
    int i = blockIdx.x * 256 + threadIdx.x;
    if (i < N) dinv[i] = rsqrtf((float)cnt[i] + 1.0f);
}

__global__ void scan_reduce(const int* __restrict__ cnt, int* __restrict__ bsums, int N) {
    __shared__ int s[256];
    int t = threadIdx.x;
    int i = blockIdx.x * 256 + t;
    s[t] = (i < N) ? cnt[i] : 0;
    __syncthreads();
    for (int d = 128; d > 0; d >>= 1) {
        if (t < d) s[t] += s[t + d];
        __syncthreads();
    }
    if (t == 0) bsums[blockIdx.x] = s[0];
}

// single block, 512 threads; nb <= 512 (N=100000 -> nb=391)
__global__ void scan_bsums(int* bsums, int nb) {
    __shared__ int s[512];
    int t = threadIdx.x;
    int v = (t < nb) ? bsums[t] : 0;
    s[t] = v;
    __syncthreads();
    for (int d = 1; d < 512; d <<= 1) {
        int x = (t >= d) ? s[t - d] : 0;
        __syncthreads();
        s[t] += x;
        __syncthreads();
    }
    if (t < nb) bsums[t] = s[t] - v;  // exclusive
}

__global__ void scan_final(const int* __restrict__ cnt, const int* __restrict__ bsums,
                           int* __restrict__ offsets, int* __restrict__ cursor, int N) {
    __shared__ int s[256];
    int t = threadIdx.x;
    int i = blockIdx.x * 256 + t;
    int v = (i < N) ? cnt[i] : 0;
    s[t] = v;
    __syncthreads();
    for (int d = 1; d < 256; d <<= 1) {
        int x = (t >= d) ? s[t - d] : 0;
        __syncthreads();
        s[t] += x;
        __syncthreads();
    }
    if (i < N) {
        int ex = s[t] - v + bsums[blockIdx.x];
        offsets[i] = ex;
        cursor[i] = ex;
    }
}

__global__ void scatter_kernel(const int* __restrict__ esrc, const int* __restrict__ edst,
                               int* __restrict__ cursor, int* __restrict__ csr_src, int E) {
    int e = blockIdx.x * 256 + threadIdx.x;
    if (e >= E) return;
    int d = edst[e];
    int pos = atomicAdd(&cursor[d], 1);
    csr_src[pos] = esrc[e];
}

// Fused GCN layer: agg (CSR gather) -> dinv scale -> 32x32 matmul (shfl) ->
// relu -> optional dinv pre-scale -> store.
// L1 variant gathers dinv[s]*ew[x_idx[s]][c] instead of reading ht.
template <bool L1>
__global__ void __launch_bounds__(256) gcn_layer(
    const float* __restrict__ ht, const int* __restrict__ x_idx,
    const float* __restrict__ ew, const float* __restrict__ dinv,
    const int* __restrict__ offsets, const int* __restrict__ cnt,
    const int* __restrict__ csr_src, const float* __restrict__ W,
    const float* __restrict__ bias, float* __restrict__ out,
    int N, int scale_next) {
    int c = threadIdx.x & 31;
    int grp = threadIdx.x >> 5;  // 0..7

    // per-lane weight row: w[k] = W[c][k]  (row c of conv_w[l])
    float w[CDIM];
    {
        const float4* Wrow = reinterpret_cast<const float4*>(W + c * CDIM);
        #pragma unroll
        for (int q = 0; q < CDIM / 4; ++q) {
            float4 t = Wrow[q];
            w[4 * q + 0] = t.x;
            w[4 * q + 1] = t.y;
            w[4 * q + 2] = t.z;
            w[4 * q + 3] = t.w;
        }
    }
    float bc = bias[c];

    for (int v0 = blockIdx.x * 8; v0 < N; v0 += gridDim.x * 8) {
        int v = v0 + grp;
        if (v >= N) continue;  // uniform across the 32-lane group
        float dv = dinv[v];
        float acc;
        if (L1)
            acc = dv * ew[x_idx[v] * CDIM + c];
        else
            acc = ht[v * CDIM + c];
        int e = offsets[v];
        int e1 = e + cnt[v];
        for (; e < e1; ++e) {
            int s = csr_src[e];
            if (L1)
                acc += dinv[s] * ew[x_idx[s] * CDIM + c];
            else
                acc += ht[s * CDIM + c];
        }
        float aggv = dv * acc;  // true (unscaled) aggregation value, channel c
        float o = bc;
        #pragma unroll
        for (int k = 0; k < CDIM; ++k)
            o = fmaf(__shfl(aggv, k, 32), w[k], o);
        o = fmaxf(o, 0.f);
        if (scale_next) o *= dv;
        out[v * CDIM + c] = o;
    }
}

// chunked segment-max over sorted batch; h >= 0 so uint-bit atomicMax is valid
#define PCHUNK 128
__global__ void pool_kernel(const float* __restrict__ h, const int* __restrict__ batch,
                            unsigned* __restrict__ pooled, int N) {
    __shared__ int sb[8 * PCHUNK];
    int t = threadIdx.x;
    int chunk0 = blockIdx.x * 8;
    int sbase = chunk0 * PCHUNK;
    for (int i = t; i < 8 * PCHUNK; i += 256)
        sb[i] = (sbase + i < N) ? batch[sbase + i] : -1;
    __syncthreads();
    int c = t & 31, cs = t >> 5;
    int i0 = (chunk0 + cs) * PCHUNK;
    if (i0 >= N) return;
    int curg = sb[cs * PCHUNK];
    float m = -1.0f;  // sentinel: nothing accumulated (h values are >= 0)
    for (int k = 0; k < PCHUNK; ++k) {
        int i = i0 + k;
        if (i >= N) break;
        int g = sb[cs * PCHUNK + k];
        float v = h[i * CDIM + c];
        if (g != curg) {
            if (m >= 0.f) atomicMax(&pooled[curg * CDIM + c], __float_as_uint(m));
            curg = g;
            m = v;
        } else {
            m = fmaxf(m, v);
        }
    }
    if (m >= 0.f && curg >= 0) atomicMax(&pooled[curg * CDIM + c], __float_as_uint(m));
}

__global__ void head_kernel(const float* __restrict__ pooled,
                            const float* __restrict__ d0_w, const float* __restrict__ d0_b,
                            const float* __restrict__ dense_w, const float* __restrict__ dense_b,
                            const float* __restrict__ fin_w, const float* __restrict__ fin_b,
                            float* __restrict__ out, int G) {
    int g = threadIdx.x;
    if (g >= G) return;
    float x[CDIM], y[CDIM];
    #pragma unroll
    for (int k = 0; k < CDIM; ++k) x[k] = pooled[g * CDIM + k];
    #pragma unroll
    for (int c = 0; c < CDIM; ++c) {
        float a = d0_b[c];
        #pragma unroll
        for (int k = 0; k < CDIM; ++k) a += x[k] * d0_w[c * CDIM + k];
        y[c] = fmaxf(a, 0.f);
    }
    #pragma unroll
    for (int k = 0; k < CDIM; ++k) x[k] = y[k];
    for (int l = 0; l < 3; ++l) {
        const float* Wl = dense_w + l * CDIM * CDIM;
        const float* bl = dense_b + l * CDIM;
        #pragma unroll
        for (int c = 0; c < CDIM; ++c) {
            float a = bl[c];
            #pragma unroll
            for (int k = 0; k < CDIM; ++k) a += x[k] * Wl[c * CDIM + k];
            y[c] = fmaxf(a, 0.f);
        }
        #pragma unroll
        for (int k = 0; k < CDIM; ++k) x[k] = y[k];
    }
    float l0 = fin_b[0], l1 = fin_b[1];
    #pragma unroll
    for (int k = 0; k < CDIM; ++k) {
        l0 += x[k] * fin_w[k];
        l1 += x[k] * fin_w[CDIM + k];
    }
    float mm = fmaxf(l0, l1);
    float lse = mm + logf(expf(l0 - mm) + expf(l1 - mm));
    out[g * 2 + 0] = l0 - lse;
    out[g * 2 + 1] = l1 - lse;
}

extern "C" void kernel_launch(void* const* d_in, const int* in_sizes, int n_in,
                              void* d_out, int out_size, void* d_ws, size_t ws_size,
                              hipStream_t stream) {
    const int* x_idx = (const int*)d_in[0];
    const int* eidx = (const int*)d_in[1];
    const int* batch = (const int*)d_in[2];
    const float* embed_w = (const float*)d_in[3];
    const float* conv_w = (const float*)d_in[4];
    const float* conv_b = (const float*)d_in[5];
    const float* d0_w = (const float*)d_in[6];
    const float* d0_b = (const float*)d_in[7];
    const float* dense_w = (const float*)d_in[8];
    const float* dense_b = (const float*)d_in[9];
    const float* fin_w = (const float*)d_in[10];
    const float* fin_b = (const float*)d_in[11];

    int N = in_sizes[0];
    int E = in_sizes[1] / 2;
    int G = out_size / 2;
    const int* esrc = eidx;
    const int* edst = eidx + E;

    char* ws = (char*)d_ws;
    size_t off = 0;
    auto take = [&](size_t bytes) -> char* {
        char* p = ws + off;
        off = (off + bytes + 255) & ~(size_t)255;
        return p;
    };
    int* cnt = (int*)take((size_t)N * 4);
    float* dinv = (float*)take((size_t)N * 4);
    int* offsets = (int*)take((size_t)N * 4);
    int* cursor = (int*)take((size_t)N * 4);
    int* bsums = (int*)take(4096 * 4);
    int* csr_src = (int*)take((size_t)E * 4);
    float* hA = (float*)take((size_t)N * CDIM * 4);
    float* hB = (float*)take((size_t)N * CDIM * 4);
    unsigned* pooled = (unsigned*)take((size_t)G * CDIM * 4);
    (void)ws_size;
    (void)n_in;

    hipMemsetAsync(cnt, 0, (size_t)N * 4, stream);
    hipMemsetAsync(pooled, 0, (size_t)G * CDIM * 4, stream);

    int EB = (E + 255) / 256;
    int NB = (N + 255) / 256;

    count_kernel<<<EB, 256, 0, stream>>>(edst, cnt, E);
    dinv_kernel<<<NB, 256, 0, stream>>>(cnt, dinv, N);
    scan_reduce<<<NB, 256, 0, stream>>>(cnt, bsums, N);
    scan_bsums<<<1, 512, 0, stream>>>(bsums, NB);
    scan_final<<<NB, 256, 0, stream>>>(cnt, bsums, offsets, cursor, N);
    scatter_kernel<<<EB, 256, 0, stream>>>(esrc, edst, cursor, csr_src, E);

    // ping-pong feature buffers; stored pre-scaled by dinv except after last layer
    int LB = 2048;  // grid-stride; amortizes per-block weight preload
    gcn_layer<true><<<LB, 256, 0, stream>>>(
        nullptr, x_idx, embed_w, dinv, offsets, cnt, csr_src,
        conv_w + 0 * CDIM * CDIM, conv_b + 0 * CDIM, hA, N, 1);
    gcn_layer<false><<<LB, 256, 0, stream>>>(
        hA, nullptr, nullptr, dinv, offsets, cnt, csr_src,
        conv_w + 1 * CDIM * CDIM, conv_b + 1 * CDIM, hB, N, 1);
    gcn_layer<false><<<LB, 256, 0, stream>>>(
        hB, nullptr, nullptr, dinv, offsets, cnt, csr_src,
        conv_w + 2 * CDIM * CDIM, conv_b + 2 * CDIM, hA, N, 1);
    gcn_layer<false><<<LB, 256, 0, stream>>>(
        hA, nullptr, nullptr, dinv, offsets, cnt, csr_src,
        conv_w + 3 * CDIM * CDIM, conv_b + 3 * CDIM, hB, N, 1);
    gcn_layer<false><<<LB, 256, 0, stream>>>(
        hB, nullptr, nullptr, dinv, offsets, cnt, csr_src,
        conv_w + 4 * CDIM * CDIM, conv_b + 4 * CDIM, hA, N, 0);

    int nchunks = (N + PCHUNK - 1) / PCHUNK;
    pool_kernel<<<(nchunks + 7) / 8, 256, 0, stream>>>(hA, batch, pooled, N);
    head_kernel<<<1, 128, 0, stream>>>((const float*)pooled, d0_w, d0_b,
                                       dense_w, dense_b, fin_w, fin_b,
                                       (float*)d_out, G);
}

// Round 3
// 484.283 us; speedup vs baseline: 1.8046x; 1.6188x over previous
//
#include <hip/hip_runtime.h>
#include <hip/hip_bf16.h>

// GCN forward: 5x (agg + linear + relu fused) + segment_max pool + MLP head.
// N=100000, E=1600000, C=32, G=128.
//
//  - CSR build via 2-level binning sort (bucket = dst>>7) to avoid the 16x
//    write amplification of a flat atomic-cursor scatter:
//      bin_kernel:   LDS histogram per 12800-edge chunk, one global atomicAdd
//                    per (block,bucket) reserves a contiguous run, packed
//                    (dstLocal<<20|src) 4B pairs written in ~64B runs.
//      fine_scatter: one block per bucket; scatter inside a ~10KB XCD-local
//                    hot window; pads each node's list to a multiple of 4
//                    with index N (an all-zero feature row).
//  - features stored pre-scaled: ht[i] = dinv[i] * h[i]; ht[N] = 0.
//  - fused layer: 32-lane group per node; int4 src-index loads give 4
//    independent 128B row gathers per iteration (ILP on the latency chain);
//    then in-register 32x32 matmul via __shfl, relu, optional dinv pre-scale.
//  - pool: chunked running-max over sorted batch, uint atomicMax flush.
//  - head: one 128-thread block, fully unrolled.

#define CDIM 32
#define BSHIFT 7
#define BSPAN 128
#define MAXBUK 800      // >= ceil(100000/128)=782
#define CHUNK 12800

__global__ void count_kernel(const int* __restrict__ edst, int* __restrict__ cnt, int E) {
    int e = blockIdx.x * 256 + threadIdx.x;
    if (e < E) atomicAdd(&cnt[edst[e]], 1);
}

// dinvx[i] = rsqrt(cnt+1) for i<N, 0 at i==N; xi2[i] = x_idx[i], 0 at i==N
__global__ void dinv_ext_kernel(const int* __restrict__ cnt, const int* __restrict__ x_idx,
                                float* __restrict__ dinvx, int* __restrict__ xi2, int N) {
    int i = blockIdx.x * 256 + threadIdx.x;
    if (i < N) {
        dinvx[i] = rsqrtf((float)cnt[i] + 1.0f);
        xi2[i] = x_idx[i];
    } else if (i == N) {
        dinvx[i] = 0.f;
        xi2[i] = 0;
    }
}

__global__ void btot_kernel(const int* __restrict__ cnt, int* __restrict__ btot, int N) {
    __shared__ int s[BSPAN];
    int b = blockIdx.x, t = threadIdx.x;  // 128 threads
    int v = b * BSPAN + t;
    s[t] = (v < N) ? cnt[v] : 0;
    __syncthreads();
    for (int d = 64; d > 0; d >>= 1) {
        if (t < d) s[t] += s[t + d];
        __syncthreads();
    }
    if (t == 0) btot[b] = s[0];
}

// single block, 1024 threads; exclusive scan of btot -> bbase, gcursor
__global__ void bscan_kernel(const int* __restrict__ btot, int* __restrict__ bbase,
                             int* __restrict__ gcursor, int nb) {
    __shared__ int s[1024];
    int t = threadIdx.x;
    int v = (t < nb) ? btot[t] : 0;
    s[t] = v;
    __syncthreads();
    for (int d = 1; d < 1024; d <<= 1) {
        int x = (t >= d) ? s[t - d] : 0;
        __syncthreads();
        s[t] += x;
        __syncthreads();
    }
    if (t < nb) {
        bbase[t] = s[t] - v;
        gcursor[t] = s[t] - v;
    }
}

// padded-count scans: value = (cnt+3)&~3
__global__ void scan_reduce(const int* __restrict__ cnt, int* __restrict__ bsums, int N) {
    __shared__ int s[256];
    int t = threadIdx.x;
    int i = blockIdx.x * 256 + t;
    s[t] = (i < N) ? ((cnt[i] + 3) & ~3) : 0;
    __syncthreads();
    for (int d = 128; d > 0; d >>= 1) {
        if (t < d) s[t] += s[t + d];
        __syncthreads();
    }
    if (t == 0) bsums[blockIdx.x] = s[0];
}

__global__ void scan_bsums(int* bsums, int nb) {
    __shared__ int s[512];
    int t = threadIdx.x;
    int v = (t < nb) ? bsums[t] : 0;
    s[t] = v;
    __syncthreads();
    for (int d = 1; d < 512; d <<= 1) {
        int x = (t >= d) ? s[t - d] : 0;
        __syncthreads();
        s[t] += x;
        __syncthreads();
    }
    if (t < nb) bsums[t] = s[t] - v;  // exclusive
}

__global__ void scan_final(const int* __restrict__ cnt, const int* __restrict__ bsums,
                           int* __restrict__ offsets4, int* __restrict__ cursor4, int N) {
    __shared__ int s[256];
    int t = threadIdx.x;
    int i = blockIdx.x * 256 + t;
    int v = (i < N) ? ((cnt[i] + 3) & ~3) : 0;
    s[t] = v;
    __syncthreads();
    for (int d = 1; d < 256; d <<= 1) {
        int x = (t >= d) ? s[t - d] : 0;
        __syncthreads();
        s[t] += x;
        __syncthreads();
    }
    if (i < N) {
        int ex = s[t] - v + bsums[blockIdx.x];
        offsets4[i] = ex;
        cursor4[i] = ex;
    }
}

// bin edges by dst>>BSHIFT; contiguous per-(block,bucket) runs in pairs[]
__global__ void __launch_bounds__(256) bin_kernel(
    const int* __restrict__ esrc, const int* __restrict__ edst,
    int* __restrict__ gcursor, unsigned* __restrict__ pairs, int E, int nbuk) {
    __shared__ int hist[MAXBUK];
    __shared__ int lcur[MAXBUK];
    int t = threadIdx.x;
    int base = blockIdx.x * CHUNK;
    int n = min(CHUNK, E - base);
    if (n <= 0) return;
    for (int i = t; i < nbuk; i += 256) hist[i] = 0;
    __syncthreads();
    for (int i = t; i < n; i += 256)
        atomicAdd(&hist[edst[base + i] >> BSHIFT], 1);
    __syncthreads();
    for (int b = t; b < nbuk; b += 256) {
        int h = hist[b];
        lcur[b] = h ? atomicAdd(&gcursor[b], h) : 0;
    }
    __syncthreads();
    for (int i = t; i < n; i += 256) {
        int d = edst[base + i];
        int s = esrc[base + i];
        int b = d >> BSHIFT;
        int pos = atomicAdd(&lcur[b], 1);
        pairs[pos] = ((unsigned)(d & (BSPAN - 1)) << 20) | (unsigned)s;
    }
}

// one block per bucket: scatter src into padded CSR; fill pads with N
__global__ void __launch_bounds__(256) fine_scatter(
    const unsigned* __restrict__ pairs, const int* __restrict__ bbase,
    const int* __restrict__ btot, int* __restrict__ cursor4,
    const int* __restrict__ cnt, const int* __restrict__ offsets4,
    int* __restrict__ csr, int N) {
    int b = blockIdx.x, t = threadIdx.x;
    int p0 = bbase[b], p1 = p0 + btot[b];
    for (int i = p0 + t; i < p1; i += 256) {
        unsigned pk = pairs[i];
        int d = (b << BSHIFT) + (int)(pk >> 20);
        int s = (int)(pk & 0xFFFFFu);
        int pos = atomicAdd(&cursor4[d], 1);
        csr[pos] = s;
    }
    __syncthreads();
    int v0 = b << BSHIFT, v1 = min(v0 + BSPAN, N);
    for (int v = v0 + t; v < v1; v += 256) {
        int c = cnt[v];
        int e = offsets4[v] + c;
        int e1 = offsets4[v] + ((c + 3) & ~3);
        for (; e < e1; ++e) csr[e] = N;  // pad -> zero feature row
    }
}

// Fused GCN layer. 32-lane group per node. int4 src loads for gather ILP.
template <bool L1>
__global__ void __launch_bounds__(256) gcn_layer(
    const float* __restrict__ ht, const int* __restrict__ xi2,
    const float* __restrict__ ew, const float* __restrict__ dinvx,
    const int* __restrict__ offsets4, const int* __restrict__ cnt,
    const int* __restrict__ csr, const float* __restrict__ W,
    const float* __restrict__ bias, float* __restrict__ out,
    int N, int scale_next) {
    int c = threadIdx.x & 31;
    int grp = threadIdx.x >> 5;  // 0..7

    float w[CDIM];
    {
        const float4* Wrow = reinterpret_cast<const float4*>(W + c * CDIM);
        #pragma unroll
        for (int q = 0; q < CDIM / 4; ++q) {
            float4 t = Wrow[q];
            w[4 * q + 0] = t.x;
            w[4 * q + 1] = t.y;
            w[4 * q + 2] = t.z;
            w[4 * q + 3] = t.w;
        }
    }
    float bc = bias[c];

    for (int v0 = blockIdx.x * 8; v0 < N; v0 += gridDim.x * 8) {
        int v = v0 + grp;
        if (v >= N) continue;  // uniform across the 32-lane group
        float dv = dinvx[v];
        float acc;
        if (L1)
            acc = dv * ew[xi2[v] * CDIM + c];
        else
            acc = ht[v * CDIM + c];
        int e = offsets4[v];
        int e1 = e + ((cnt[v] + 3) & ~3);
        for (; e < e1; e += 4) {
            int4 s4 = *reinterpret_cast<const int4*>(&csr[e]);
            if (L1) {
                acc += dinvx[s4.x] * ew[xi2[s4.x] * CDIM + c];
                acc += dinvx[s4.y] * ew[xi2[s4.y] * CDIM + c];
                acc += dinvx[s4.z] * ew[xi2[s4.z] * CDIM + c];
                acc += dinvx[s4.w] * ew[xi2[s4.w] * CDIM + c];
            } else {
                float a0 = ht[s4.x * CDIM + c];
                float a1 = ht[s4.y * CDIM + c];
                float a2 = ht[s4.z * CDIM + c];
                float a3 = ht[s4.w * CDIM + c];
                acc += (a0 + a1) + (a2 + a3);
            }
        }
        float aggv = dv * acc;  // true aggregation value, channel c
        float o = bc;
        #pragma unroll
        for (int k = 0; k < CDIM; ++k)
            o = fmaf(__shfl(aggv, k, 32), w[k], o);
        o = fmaxf(o, 0.f);
        if (scale_next) o *= dv;
        out[v * CDIM + c] = o;
    }
}

// chunked segment-max over sorted batch; h >= 0 so uint-bit atomicMax is valid
#define PCHUNK 128
__global__ void pool_kernel(const float* __restrict__ h, const int* __restrict__ batch,
                            unsigned* __restrict__ pooled, int N) {
    __shared__ int sb[8 * PCHUNK];
    int t = threadIdx.x;
    int chunk0 = blockIdx.x * 8;
    int sbase = chunk0 * PCHUNK;
    for (int i = t; i < 8 * PCHUNK; i += 256)
        sb[i] = (sbase + i < N) ? batch[sbase + i] : -1;
    __syncthreads();
    int c = t & 31, cs = t >> 5;
    int i0 = (chunk0 + cs) * PCHUNK;
    if (i0 >= N) return;
    int curg = sb[cs * PCHUNK];
    float m = -1.0f;  // sentinel: nothing accumulated (h values are >= 0)
    for (int k = 0; k < PCHUNK; ++k) {
        int i = i0 + k;
        if (i >= N) break;
        int g = sb[cs * PCHUNK + k];
        float v = h[i * CDIM + c];
        if (g != curg) {
            if (m >= 0.f) atomicMax(&pooled[curg * CDIM + c], __float_as_uint(m));
            curg = g;
            m = v;
        } else {
            m = fmaxf(m, v);
        }
    }
    if (m >= 0.f && curg >= 0) atomicMax(&pooled[curg * CDIM + c], __float_as_uint(m));
}

__global__ void head_kernel(const float* __restrict__ pooled,
                            const float* __restrict__ d0_w, const float* __restrict__ d0_b,
                            const float* __restrict__ dense_w, const float* __restrict__ dense_b,
                            const float* __restrict__ fin_w, const float* __restrict__ fin_b,
                            float* __restrict__ out, int G) {
    int g = threadIdx.x;
    if (g >= G) return;
    float x[CDIM], y[CDIM];
    #pragma unroll
    for (int k = 0; k < CDIM; ++k) x[k] = pooled[g * CDIM + k];
    #pragma unroll
    for (int c = 0; c < CDIM; ++c) {
        float a = d0_b[c];
        #pragma unroll
        for (int k = 0; k < CDIM; ++k) a += x[k] * d0_w[c * CDIM + k];
        y[c] = fmaxf(a, 0.f);
    }
    #pragma unroll
    for (int k = 0; k < CDIM; ++k) x[k] = y[k];
    for (int l = 0; l < 3; ++l) {
        const float* Wl = dense_w + l * CDIM * CDIM;
        const float* bl = dense_b + l * CDIM;
        #pragma unroll
        for (int c = 0; c < CDIM; ++c) {
            float a = bl[c];
            #pragma unroll
            for (int k = 0; k < CDIM; ++k) a += x[k] * Wl[c * CDIM + k];
            y[c] = fmaxf(a, 0.f);
        }
        #pragma unroll
        for (int k = 0; k < CDIM; ++k) x[k] = y[k];
    }
    float l0 = fin_b[0], l1 = fin_b[1];
    #pragma unroll
    for (int k = 0; k < CDIM; ++k) {
        l0 += x[k] * fin_w[k];
        l1 += x[k] * fin_w[CDIM + k];
    }
    float mm = fmaxf(l0, l1);
    float lse = mm + logf(expf(l0 - mm) + expf(l1 - mm));
    out[g * 2 + 0] = l0 - lse;
    out[g * 2 + 1] = l1 - lse;
}

extern "C" void kernel_launch(void* const* d_in, const int* in_sizes, int n_in,
                              void* d_out, int out_size, void* d_ws, size_t ws_size,
                              hipStream_t stream) {
    const int* x_idx = (const int*)d_in[0];
    const int* eidx = (const int*)d_in[1];
    const int* batch = (const int*)d_in[2];
    const float* embed_w = (const float*)d_in[3];
    const float* conv_w = (const float*)d_in[4];
    const float* conv_b = (const float*)d_in[5];
    const float* d0_w = (const float*)d_in[6];
    const float* d0_b = (const float*)d_in[7];
    const float* dense_w = (const float*)d_in[8];
    const float* dense_b = (const float*)d_in[9];
    const float* fin_w = (const float*)d_in[10];
    const float* fin_b = (const float*)d_in[11];

    int N = in_sizes[0];
    int E = in_sizes[1] / 2;
    int G = out_size / 2;
    const int* esrc = eidx;
    const int* edst = eidx + E;
    int nbuk = (N + BSPAN - 1) >> BSHIFT;  // 782

    char* ws = (char*)d_ws;
    size_t off = 0;
    auto take = [&](size_t bytes) -> char* {
        char* p = ws + off;
        off = (off + bytes + 255) & ~(size_t)255;
        return p;
    };
    int* cnt = (int*)take((size_t)N * 4);
    float* dinvx = (float*)take((size_t)(N + 1) * 4);
    int* xi2 = (int*)take((size_t)(N + 1) * 4);
    int* offsets4 = (int*)take((size_t)N * 4);
    int* cursor4 = (int*)take((size_t)N * 4);
    int* bsums = (int*)take(4096 * 4);
    int* btot = (int*)take(MAXBUK * 4);
    int* bbase = (int*)take(MAXBUK * 4);
    int* gcursor = (int*)take(MAXBUK * 4);
    unsigned* pairs = (unsigned*)take((size_t)E * 4);
    int* csr = (int*)take((size_t)(E + 3 * N + 256) * 4);
    float* hA = (float*)take((size_t)(N + 1) * CDIM * 4);
    float* hB = (float*)take((size_t)(N + 1) * CDIM * 4);
    unsigned* pooled = (unsigned*)take((size_t)G * CDIM * 4);
    (void)ws_size;
    (void)n_in;

    hipMemsetAsync(cnt, 0, (size_t)N * 4, stream);
    hipMemsetAsync(pooled, 0, (size_t)G * CDIM * 4, stream);
    hipMemsetAsync(hA + (size_t)N * CDIM, 0, CDIM * 4, stream);  // zero row N
    hipMemsetAsync(hB + (size_t)N * CDIM, 0, CDIM * 4, stream);

    int EB = (E + 255) / 256;
    int NB = (N + 255) / 256;

    count_kernel<<<EB, 256, 0, stream>>>(edst, cnt, E);
    dinv_ext_kernel<<<(N + 256) / 256, 256, 0, stream>>>(cnt, x_idx, dinvx, xi2, N);
    btot_kernel<<<nbuk, BSPAN, 0, stream>>>(cnt, btot, N);
    bscan_kernel<<<1, 1024, 0, stream>>>(btot, bbase, gcursor, nbuk);
    scan_reduce<<<NB, 256, 0, stream>>>(cnt, bsums, N);
    scan_bsums<<<1, 512, 0, stream>>>(bsums, NB);
    scan_final<<<NB, 256, 0, stream>>>(cnt, bsums, offsets4, cursor4, N);
    bin_kernel<<<(E + CHUNK - 1) / CHUNK, 256, 0, stream>>>(esrc, edst, gcursor, pairs, E, nbuk);
    fine_scatter<<<nbuk, 256, 0, stream>>>(pairs, bbase, btot, cursor4, cnt, offsets4, csr, N);

    int LB = 2048;  // grid-stride; amortizes per-block weight preload
    gcn_layer<true><<<LB, 256, 0, stream>>>(
        nullptr, xi2, embed_w, dinvx, offsets4, cnt, csr,
        conv_w + 0 * CDIM * CDIM, conv_b + 0 * CDIM, hA, N, 1);
    gcn_layer<false><<<LB, 256, 0, stream>>>(
        hA, nullptr, nullptr, dinvx, offsets4, cnt, csr,
        conv_w + 1 * CDIM * CDIM, conv_b + 1 * CDIM, hB, N, 1);
    gcn_layer<false><<<LB, 256, 0, stream>>>(
        hB, nullptr, nullptr, dinvx, offsets4, cnt, csr,
        conv_w + 2 * CDIM * CDIM, conv_b + 2 * CDIM, hA, N, 1);
    gcn_layer<false><<<LB, 256, 0, stream>>>(
        hA, nullptr, nullptr, dinvx, offsets4, cnt, csr,
        conv_w + 3 * CDIM * CDIM, conv_b + 3 * CDIM, hB, N, 1);
    gcn_layer<false><<<LB, 256, 0, stream>>>(
        hB, nullptr, nullptr, dinvx, offsets4, cnt, csr,
        conv_w + 4 * CDIM * CDIM, conv_b + 4 * CDIM, hA, N, 0);

    int nchunks = (N + PCHUNK - 1) / PCHUNK;
    pool_kernel<<<(nchunks + 7) / 8, 256, 0, stream>>>(hA, batch, pooled, N);
    head_kernel<<<1, 128, 0, stream>>>((const float*)pooled, d0_w, d0_b,
                                       dense_w, dense_b, fin_w, fin_b,
                                       (float*)d_out, G);
}

// Round 4
// 404.562 us; speedup vs baseline: 2.1603x; 1.1971x over previous
//
#include <hip/hip_runtime.h>
#include <hip/hip_bf16.h>

// GCN forward: 5x (agg + linear + relu fused) + segment_max pool + MLP head.
// N=100000, E=1600000, C=32, G=128.
//
//  - CSR build via 2-level binning sort (bucket = dst>>7). NO per-node global
//    atomics anywhere:
//      bucket_count: per-chunk LDS hist (782 buckets) -> global btot adds.
//      bin_kernel:   LDS hist reserves contiguous per-(block,bucket) runs,
//                    writes packed (dstLocal<<20|src) pairs in ~64B runs.
//      node_count:   per bucket, LDS 128-ctr hist of pairs -> cnt/dinvx/xi2.
//      csr_scatter:  per bucket, LDS cursors from offsets4 -> csr (+pad to x4
//                    with index N, an all-zero feature row).
//  - features stored pre-scaled: ht[i] = dinv[i] * h[i]; ht[N] = 0.
//  - fused layer: 32-lane group per node; int4 src-index loads give 4
//    independent 128B row gathers per iteration; in-register 32x32 matmul via
//    __shfl, relu, optional dinv pre-scale.
//  - pool: chunked running-max over sorted batch, uint atomicMax flush.
//  - head: one 128-thread block, fully unrolled.

#define CDIM 32
#define BSHIFT 7
#define BSPAN 128
#define MAXBUK 800      // >= ceil(100000/128)=782
#define CHUNK 12800

// per-chunk LDS histogram of dst buckets -> btot
__global__ void __launch_bounds__(256) bucket_count(
    const int* __restrict__ edst, int* __restrict__ btot, int E, int nbuk) {
    __shared__ int hist[MAXBUK];
    int t = threadIdx.x;
    int base = blockIdx.x * CHUNK;
    int n = min(CHUNK, E - base);
    if (n <= 0) return;
    for (int i = t; i < nbuk; i += 256) hist[i] = 0;
    __syncthreads();
    for (int i = t; i < n; i += 256)
        atomicAdd(&hist[edst[base + i] >> BSHIFT], 1);
    __syncthreads();
    for (int b = t; b < nbuk; b += 256) {
        int h = hist[b];
        if (h) atomicAdd(&btot[b], h);
    }
}

// single block, 1024 threads; exclusive scan of btot -> bbase, gcursor
__global__ void bscan_kernel(const int* __restrict__ btot, int* __restrict__ bbase,
                             int* __restrict__ gcursor, int nb) {
    __shared__ int s[1024];
    int t = threadIdx.x;
    int v = (t < nb) ? btot[t] : 0;
    s[t] = v;
    __syncthreads();
    for (int d = 1; d < 1024; d <<= 1) {
        int x = (t >= d) ? s[t - d] : 0;
        __syncthreads();
        s[t] += x;
        __syncthreads();
    }
    if (t < nb) {
        bbase[t] = s[t] - v;
        gcursor[t] = s[t] - v;
    }
}

// bin edges by dst>>BSHIFT; contiguous per-(block,bucket) runs in pairs[]
__global__ void __launch_bounds__(256) bin_kernel(
    const int* __restrict__ esrc, const int* __restrict__ edst,
    int* __restrict__ gcursor, unsigned* __restrict__ pairs, int E, int nbuk) {
    __shared__ int hist[MAXBUK];
    __shared__ int lcur[MAXBUK];
    int t = threadIdx.x;
    int base = blockIdx.x * CHUNK;
    int n = min(CHUNK, E - base);
    if (n <= 0) return;
    for (int i = t; i < nbuk; i += 256) hist[i] = 0;
    __syncthreads();
    for (int i = t; i < n; i += 256)
        atomicAdd(&hist[edst[base + i] >> BSHIFT], 1);
    __syncthreads();
    for (int b = t; b < nbuk; b += 256) {
        int h = hist[b];
        lcur[b] = h ? atomicAdd(&gcursor[b], h) : 0;
    }
    __syncthreads();
    for (int i = t; i < n; i += 256) {
        int d = edst[base + i];
        int s = esrc[base + i];
        int b = d >> BSHIFT;
        int pos = atomicAdd(&lcur[b], 1);
        pairs[pos] = ((unsigned)(d & (BSPAN - 1)) << 20) | (unsigned)s;
    }
}

// per bucket: LDS histogram of dstLocal -> cnt, dinvx, xi2 (coalesced writes)
__global__ void __launch_bounds__(256) node_count(
    const unsigned* __restrict__ pairs, const int* __restrict__ bbase,
    const int* __restrict__ btot, const int* __restrict__ x_idx,
    int* __restrict__ cnt, float* __restrict__ dinvx, int* __restrict__ xi2,
    int N) {
    __shared__ int h[BSPAN];
    int b = blockIdx.x, t = threadIdx.x;
    if (t < BSPAN) h[t] = 0;
    __syncthreads();
    int p0 = bbase[b], p1 = p0 + btot[b];
    for (int i = p0 + t; i < p1; i += 256)
        atomicAdd(&h[pairs[i] >> 20], 1);
    __syncthreads();
    if (t < BSPAN) {
        int v = (b << BSHIFT) + t;
        if (v < N) {
            int c = h[t];
            cnt[v] = c;
            dinvx[v] = rsqrtf((float)c + 1.0f);
            xi2[v] = x_idx[v];
        }
    }
    if (b == 0 && t == 255) {  // sentinel row N
        dinvx[N] = 0.f;
        xi2[N] = 0;
    }
}

// padded-count scans: value = (cnt+3)&~3
__global__ void scan_reduce(const int* __restrict__ cnt, int* __restrict__ bsums, int N) {
    __shared__ int s[256];
    int t = threadIdx.x;
    int i = blockIdx.x * 256 + t;
    s[t] = (i < N) ? ((cnt[i] + 3) & ~3) : 0;
    __syncthreads();
    for (int d = 128; d > 0; d >>= 1) {
        if (t < d) s[t] += s[t + d];
        __syncthreads();
    }
    if (t == 0) bsums[blockIdx.x] = s[0];
}

__global__ void scan_bsums(int* bsums, int nb) {
    __shared__ int s[512];
    int t = threadIdx.x;
    int v = (t < nb) ? bsums[t] : 0;
    s[t] = v;
    __syncthreads();
    for (int d = 1; d < 512; d <<= 1) {
        int x = (t >= d) ? s[t - d] : 0;
        __syncthreads();
        s[t] += x;
        __syncthreads();
    }
    if (t < nb) bsums[t] = s[t] - v;  // exclusive
}

__global__ void scan_final(const int* __restrict__ cnt, const int* __restrict__ bsums,
                           int* __restrict__ offsets4, int N) {
    __shared__ int s[256];
    int t = threadIdx.x;
    int i = blockIdx.x * 256 + t;
    int v = (i < N) ? ((cnt[i] + 3) & ~3) : 0;
    s[t] = v;
    __syncthreads();
    for (int d = 1; d < 256; d <<= 1) {
        int x = (t >= d) ? s[t - d] : 0;
        __syncthreads();
        s[t] += x;
        __syncthreads();
    }
    if (i < N) offsets4[i] = s[t] - v + bsums[blockIdx.x];
}

// per bucket: scatter src into padded CSR via LDS cursors; pad to x4 with N
__global__ void __launch_bounds__(256) csr_scatter(
    const unsigned* __restrict__ pairs, const int* __restrict__ bbase,
    const int* __restrict__ btot, const int* __restrict__ offsets4,
    int* __restrict__ csr, int N) {
    __shared__ int lcur[BSPAN];
    __shared__ int obase[BSPAN];
    int b = blockIdx.x, t = threadIdx.x;
    int v0 = b << BSHIFT;
    if (t < BSPAN) {
        int v = v0 + t;
        int o = (v < N) ? offsets4[v] : 0;
        lcur[t] = o;
        obase[t] = o;
    }
    __syncthreads();
    int p0 = bbase[b], p1 = p0 + btot[b];
    for (int i = p0 + t; i < p1; i += 256) {
        unsigned pk = pairs[i];
        int pos = atomicAdd(&lcur[pk >> 20], 1);
        csr[pos] = (int)(pk & 0xFFFFFu);
    }
    __syncthreads();
    if (t < BSPAN) {
        int v = v0 + t;
        if (v < N) {
            int e = lcur[t];  // == offsets4[v] + cnt[v]
            int e1 = obase[t] + ((e - obase[t] + 3) & ~3);
            for (; e < e1; ++e) csr[e] = N;  // pad -> zero feature row
        }
    }
}

// Fused GCN layer. 32-lane group per node. int4 src loads for gather ILP.
template <bool L1>
__global__ void __launch_bounds__(256) gcn_layer(
    const float* __restrict__ ht, const int* __restrict__ xi2,
    const float* __restrict__ ew, const float* __restrict__ dinvx,
    const int* __restrict__ offsets4, const int* __restrict__ cnt,
    const int* __restrict__ csr, const float* __restrict__ W,
    const float* __restrict__ bias, float* __restrict__ out,
    int N, int scale_next) {
    int c = threadIdx.x & 31;
    int grp = threadIdx.x >> 5;  // 0..7

    float w[CDIM];
    {
        const float4* Wrow = reinterpret_cast<const float4*>(W + c * CDIM);
        #pragma unroll
        for (int q = 0; q < CDIM / 4; ++q) {
            float4 t = Wrow[q];
            w[4 * q + 0] = t.x;
            w[4 * q + 1] = t.y;
            w[4 * q + 2] = t.z;
            w[4 * q + 3] = t.w;
        }
    }
    float bc = bias[c];

    for (int v0 = blockIdx.x * 8; v0 < N; v0 += gridDim.x * 8) {
        int v = v0 + grp;
        if (v >= N) continue;  // uniform across the 32-lane group
        float dv = dinvx[v];
        float acc;
        if (L1)
            acc = dv * ew[xi2[v] * CDIM + c];
        else
            acc = ht[v * CDIM + c];
        int e = offsets4[v];
        int e1 = e + ((cnt[v] + 3) & ~3);
        for (; e < e1; e += 4) {
            int4 s4 = *reinterpret_cast<const int4*>(&csr[e]);
            if (L1) {
                acc += dinvx[s4.x] * ew[xi2[s4.x] * CDIM + c];
                acc += dinvx[s4.y] * ew[xi2[s4.y] * CDIM + c];
                acc += dinvx[s4.z] * ew[xi2[s4.z] * CDIM + c];
                acc += dinvx[s4.w] * ew[xi2[s4.w] * CDIM + c];
            } else {
                float a0 = ht[s4.x * CDIM + c];
                float a1 = ht[s4.y * CDIM + c];
                float a2 = ht[s4.z * CDIM + c];
                float a3 = ht[s4.w * CDIM + c];
                acc += (a0 + a1) + (a2 + a3);
            }
        }
        float aggv = dv * acc;  // true aggregation value, channel c
        float o = bc;
        #pragma unroll
        for (int k = 0; k < CDIM; ++k)
            o = fmaf(__shfl(aggv, k, 32), w[k], o);
        o = fmaxf(o, 0.f);
        if (scale_next) o *= dv;
        out[v * CDIM + c] = o;
    }
}

// chunked segment-max over sorted batch; h >= 0 so uint-bit atomicMax is valid
#define PCHUNK 128
__global__ void pool_kernel(const float* __restrict__ h, const int* __restrict__ batch,
                            unsigned* __restrict__ pooled, int N) {
    __shared__ int sb[8 * PCHUNK];
    int t = threadIdx.x;
    int chunk0 = blockIdx.x * 8;
    int sbase = chunk0 * PCHUNK;
    for (int i = t; i < 8 * PCHUNK; i += 256)
        sb[i] = (sbase + i < N) ? batch[sbase + i] : -1;
    __syncthreads();
    int c = t & 31, cs = t >> 5;
    int i0 = (chunk0 + cs) * PCHUNK;
    if (i0 >= N) return;
    int curg = sb[cs * PCHUNK];
    float m = -1.0f;  // sentinel: nothing accumulated (h values are >= 0)
    for (int k = 0; k < PCHUNK; ++k) {
        int i = i0 + k;
        if (i >= N) break;
        int g = sb[cs * PCHUNK + k];
        float v = h[i * CDIM + c];
        if (g != curg) {
            if (m >= 0.f) atomicMax(&pooled[curg * CDIM + c], __float_as_uint(m));
            curg = g;
            m = v;
        } else {
            m = fmaxf(m, v);
        }
    }
    if (m >= 0.f && curg >= 0) atomicMax(&pooled[curg * CDIM + c], __float_as_uint(m));
}

__global__ void head_kernel(const float* __restrict__ pooled,
                            const float* __restrict__ d0_w, const float* __restrict__ d0_b,
                            const float* __restrict__ dense_w, const float* __restrict__ dense_b,
                            const float* __restrict__ fin_w, const float* __restrict__ fin_b,
                            float* __restrict__ out, int G) {
    int g = threadIdx.x;
    if (g >= G) return;
    float x[CDIM], y[CDIM];
    #pragma unroll
    for (int k = 0; k < CDIM; ++k) x[k] = pooled[g * CDIM + k];
    #pragma unroll
    for (int c = 0; c < CDIM; ++c) {
        float a = d0_b[c];
        #pragma unroll
        for (int k = 0; k < CDIM; ++k) a += x[k] * d0_w[c * CDIM + k];
        y[c] = fmaxf(a, 0.f);
    }
    #pragma unroll
    for (int k = 0; k < CDIM; ++k) x[k] = y[k];
    for (int l = 0; l < 3; ++l) {
        const float* Wl = dense_w + l * CDIM * CDIM;
        const float* bl = dense_b + l * CDIM;
        #pragma unroll
        for (int c = 0; c < CDIM; ++c) {
            float a = bl[c];
            #pragma unroll
            for (int k = 0; k < CDIM; ++k) a += x[k] * Wl[c * CDIM + k];
            y[c] = fmaxf(a, 0.f);
        }
        #pragma unroll
        for (int k = 0; k < CDIM; ++k) x[k] = y[k];
    }
    float l0 = fin_b[0], l1 = fin_b[1];
    #pragma unroll
    for (int k = 0; k < CDIM; ++k) {
        l0 += x[k] * fin_w[k];
        l1 += x[k] * fin_w[CDIM + k];
    }
    float mm = fmaxf(l0, l1);
    float lse = mm + logf(expf(l0 - mm) + expf(l1 - mm));
    out[g * 2 + 0] = l0 - lse;
    out[g * 2 + 1] = l1 - lse;
}

extern "C" void kernel_launch(void* const* d_in, const int* in_sizes, int n_in,
                              void* d_out, int out_size, void* d_ws, size_t ws_size,
                              hipStream_t stream) {
    const int* x_idx = (const int*)d_in[0];
    const int* eidx = (const int*)d_in[1];
    const int* batch = (const int*)d_in[2];
    const float* embed_w = (const float*)d_in[3];
    const float* conv_w = (const float*)d_in[4];
    const float* conv_b = (const float*)d_in[5];
    const float* d0_w = (const float*)d_in[6];
    const float* d0_b = (const float*)d_in[7];
    const float* dense_w = (const float*)d_in[8];
    const float* dense_b = (const float*)d_in[9];
    const float* fin_w = (const float*)d_in[10];
    const float* fin_b = (const float*)d_in[11];

    int N = in_sizes[0];
    int E = in_sizes[1] / 2;
    int G = out_size / 2;
    const int* esrc = eidx;
    const int* edst = eidx + E;
    int nbuk = (N + BSPAN - 1) >> BSHIFT;  // 782

    char* ws = (char*)d_ws;
    size_t off = 0;
    auto take = [&](size_t bytes) -> char* {
        char* p = ws + off;
        off = (off + bytes + 255) & ~(size_t)255;
        return p;
    };
    int* cnt = (int*)take((size_t)N * 4);
    float* dinvx = (float*)take((size_t)(N + 1) * 4);
    int* xi2 = (int*)take((size_t)(N + 1) * 4);
    int* offsets4 = (int*)take((size_t)N * 4);
    int* bsums = (int*)take(4096 * 4);
    int* btot = (int*)take(MAXBUK * 4);
    int* bbase = (int*)take(MAXBUK * 4);
    int* gcursor = (int*)take(MAXBUK * 4);
    unsigned* pairs = (unsigned*)take((size_t)E * 4);
    int* csr = (int*)take((size_t)(E + 3 * N + 256) * 4);
    float* hA = (float*)take((size_t)(N + 1) * CDIM * 4);
    float* hB = (float*)take((size_t)(N + 1) * CDIM * 4);
    unsigned* pooled = (unsigned*)take((size_t)G * CDIM * 4);
    (void)ws_size;
    (void)n_in;

    hipMemsetAsync(btot, 0, MAXBUK * 4, stream);
    hipMemsetAsync(pooled, 0, (size_t)G * CDIM * 4, stream);
    hipMemsetAsync(hA + (size_t)N * CDIM, 0, CDIM * 4, stream);  // zero row N
    hipMemsetAsync(hB + (size_t)N * CDIM, 0, CDIM * 4, stream);

    int NB = (N + 255) / 256;
    int CB = (E + CHUNK - 1) / CHUNK;

    bucket_count<<<CB, 256, 0, stream>>>(edst, btot, E, nbuk);
    bscan_kernel<<<1, 1024, 0, stream>>>(btot, bbase, gcursor, nbuk);
    bin_kernel<<<CB, 256, 0, stream>>>(esrc, edst, gcursor, pairs, E, nbuk);
    node_count<<<nbuk, 256, 0, stream>>>(pairs, bbase, btot, x_idx, cnt, dinvx, xi2, N);
    scan_reduce<<<NB, 256, 0, stream>>>(cnt, bsums, N);
    scan_bsums<<<1, 512, 0, stream>>>(bsums, NB);
    scan_final<<<NB, 256, 0, stream>>>(cnt, bsums, offsets4, N);
    csr_scatter<<<nbuk, 256, 0, stream>>>(pairs, bbase, btot, offsets4, csr, N);

    int LB = 2048;  // grid-stride; amortizes per-block weight preload
    gcn_layer<true><<<LB, 256, 0, stream>>>(
        nullptr, xi2, embed_w, dinvx, offsets4, cnt, csr,
        conv_w + 0 * CDIM * CDIM, conv_b + 0 * CDIM, hA, N, 1);
    gcn_layer<false><<<LB, 256, 0, stream>>>(
        hA, nullptr, nullptr, dinvx, offsets4, cnt, csr,
        conv_w + 1 * CDIM * CDIM, conv_b + 1 * CDIM, hB, N, 1);
    gcn_layer<false><<<LB, 256, 0, stream>>>(
        hB, nullptr, nullptr, dinvx, offsets4, cnt, csr,
        conv_w + 2 * CDIM * CDIM, conv_b + 2 * CDIM, hA, N, 1);
    gcn_layer<false><<<LB, 256, 0, stream>>>(
        hA, nullptr, nullptr, dinvx, offsets4, cnt, csr,
        conv_w + 3 * CDIM * CDIM, conv_b + 3 * CDIM, hB, N, 1);
    gcn_layer<false><<<LB, 256, 0, stream>>>(
        hB, nullptr, nullptr, dinvx, offsets4, cnt, csr,
        conv_w + 4 * CDIM * CDIM, conv_b + 4 * CDIM, hA, N, 0);

    int nchunks = (N + PCHUNK - 1) / PCHUNK;
    pool_kernel<<<(nchunks + 7) / 8, 256, 0, stream>>>(hA, batch, pooled, N);
    head_kernel<<<1, 128, 0, stream>>>((const float*)pooled, d0_w, d0_b,
                                       dense_w, dense_b, fin_w, fin_b,
                                       (float*)d_out, G);
}

// Round 5
// 354.256 us; speedup vs baseline: 2.4670x; 1.1420x over previous
//
#include <hip/hip_runtime.h>
#include <hip/hip_bf16.h>

// GCN forward: 5x (agg + linear + relu fused) + segment_max pool + MLP head.
// N=100000, E=1600000, C=32, G=128.
//
//  - CSR build via 2-level binning sort (bucket = dst>>7). NO per-node global
//    atomics anywhere:
//      bucket_count: per-chunk LDS hist (782 buckets) -> global btot adds.
//      bin_kernel:   LDS hist reserves contiguous per-(block,bucket) runs,
//                    writes packed (dstLocal<<20|src) pairs in ~64B runs.
//      node_count:   per bucket, LDS 128-ctr hist of pairs -> cnt/dinvx/xi2.
//      csr_scatter:  per bucket, LDS cursors from offsets4 -> csr (+pad to x4
//                    with index N, an all-zero feature row).
//  - features stored pre-scaled: ht[i] = dinv[i] * h[i]; ht[N] = 0.
//  - fused layer: 32-lane group per node; int4 src-index loads give 4
//    independent 128B row gathers per iteration; in-register 32x32 matmul via
//    __shfl, relu, optional dinv pre-scale.
//  - pool: chunked running-max over sorted batch, uint atomicMax flush.
//  - head: 32-lane group per graph (16 blocks x 256), coalesced float4 weight
//    rows + __shfl matmul + butterfly logit reduce. (The old 1-block serial
//    head was 71-93us of pure load latency on an idle GPU.)

#define CDIM 32
#define BSHIFT 7
#define BSPAN 128
#define MAXBUK 800      // >= ceil(100000/128)=782
#define CHUNK 12800

// per-chunk LDS histogram of dst buckets -> btot
__global__ void __launch_bounds__(256) bucket_count(
    const int* __restrict__ edst, int* __restrict__ btot, int E, int nbuk) {
    __shared__ int hist[MAXBUK];
    int t = threadIdx.x;
    int base = blockIdx.x * CHUNK;
    int n = min(CHUNK, E - base);
    if (n <= 0) return;
    for (int i = t; i < nbuk; i += 256) hist[i] = 0;
    __syncthreads();
    for (int i = t; i < n; i += 256)
        atomicAdd(&hist[edst[base + i] >> BSHIFT], 1);
    __syncthreads();
    for (int b = t; b < nbuk; b += 256) {
        int h = hist[b];
        if (h) atomicAdd(&btot[b], h);
    }
}

// single block, 1024 threads; exclusive scan of btot -> bbase, gcursor
__global__ void bscan_kernel(const int* __restrict__ btot, int* __restrict__ bbase,
                             int* __restrict__ gcursor, int nb) {
    __shared__ int s[1024];
    int t = threadIdx.x;
    int v = (t < nb) ? btot[t] : 0;
    s[t] = v;
    __syncthreads();
    for (int d = 1; d < 1024; d <<= 1) {
        int x = (t >= d) ? s[t - d] : 0;
        __syncthreads();
        s[t] += x;
        __syncthreads();
    }
    if (t < nb) {
        bbase[t] = s[t] - v;
        gcursor[t] = s[t] - v;
    }
}

// bin edges by dst>>BSHIFT; contiguous per-(block,bucket) runs in pairs[]
__global__ void __launch_bounds__(256) bin_kernel(
    const int* __restrict__ esrc, const int* __restrict__ edst,
    int* __restrict__ gcursor, unsigned* __restrict__ pairs, int E, int nbuk) {
    __shared__ int hist[MAXBUK];
    __shared__ int lcur[MAXBUK];
    int t = threadIdx.x;
    int base = blockIdx.x * CHUNK;
    int n = min(CHUNK, E - base);
    if (n <= 0) return;
    for (int i = t; i < nbuk; i += 256) hist[i] = 0;
    __syncthreads();
    for (int i = t; i < n; i += 256)
        atomicAdd(&hist[edst[base + i] >> BSHIFT], 1);
    __syncthreads();
    for (int b = t; b < nbuk; b += 256) {
        int h = hist[b];
        lcur[b] = h ? atomicAdd(&gcursor[b], h) : 0;
    }
    __syncthreads();
    for (int i = t; i < n; i += 256) {
        int d = edst[base + i];
        int s = esrc[base + i];
        int b = d >> BSHIFT;
        int pos = atomicAdd(&lcur[b], 1);
        pairs[pos] = ((unsigned)(d & (BSPAN - 1)) << 20) | (unsigned)s;
    }
}

// per bucket: LDS histogram of dstLocal -> cnt, dinvx, xi2 (coalesced writes)
__global__ void __launch_bounds__(256) node_count(
    const unsigned* __restrict__ pairs, const int* __restrict__ bbase,
    const int* __restrict__ btot, const int* __restrict__ x_idx,
    int* __restrict__ cnt, float* __restrict__ dinvx, int* __restrict__ xi2,
    int N) {
    __shared__ int h[BSPAN];
    int b = blockIdx.x, t = threadIdx.x;
    if (t < BSPAN) h[t] = 0;
    __syncthreads();
    int p0 = bbase[b], p1 = p0 + btot[b];
    for (int i = p0 + t; i < p1; i += 256)
        atomicAdd(&h[pairs[i] >> 20], 1);
    __syncthreads();
    if (t < BSPAN) {
        int v = (b << BSHIFT) + t;
        if (v < N) {
            int c = h[t];
            cnt[v] = c;
            dinvx[v] = rsqrtf((float)c + 1.0f);
            xi2[v] = x_idx[v];
        }
    }
    if (b == 0 && t == 255) {  // sentinel row N
        dinvx[N] = 0.f;
        xi2[N] = 0;
    }
}

// padded-count scans: value = (cnt+3)&~3
__global__ void scan_reduce(const int* __restrict__ cnt, int* __restrict__ bsums, int N) {
    __shared__ int s[256];
    int t = threadIdx.x;
    int i = blockIdx.x * 256 + t;
    s[t] = (i < N) ? ((cnt[i] + 3) & ~3) : 0;
    __syncthreads();
    for (int d = 128; d > 0; d >>= 1) {
        if (t < d) s[t] += s[t + d];
        __syncthreads();
    }
    if (t == 0) bsums[blockIdx.x] = s[0];
}

__global__ void scan_bsums(int* bsums, int nb) {
    __shared__ int s[512];
    int t = threadIdx.x;
    int v = (t < nb) ? bsums[t] : 0;
    s[t] = v;
    __syncthreads();
    for (int d = 1; d < 512; d <<= 1) {
        int x = (t >= d) ? s[t - d] : 0;
        __syncthreads();
        s[t] += x;
        __syncthreads();
    }
    if (t < nb) bsums[t] = s[t] - v;  // exclusive
}

__global__ void scan_final(const int* __restrict__ cnt, const int* __restrict__ bsums,
                           int* __restrict__ offsets4, int N) {
    __shared__ int s[256];
    int t = threadIdx.x;
    int i = blockIdx.x * 256 + t;
    int v = (i < N) ? ((cnt[i] + 3) & ~3) : 0;
    s[t] = v;
    __syncthreads();
    for (int d = 1; d < 256; d <<= 1) {
        int x = (t >= d) ? s[t - d] : 0;
        __syncthreads();
        s[t] += x;
        __syncthreads();
    }
    if (i < N) offsets4[i] = s[t] - v + bsums[blockIdx.x];
}

// per bucket: scatter src into padded CSR via LDS cursors; pad to x4 with N
__global__ void __launch_bounds__(256) csr_scatter(
    const unsigned* __restrict__ pairs, const int* __restrict__ bbase,
    const int* __restrict__ btot, const int* __restrict__ offsets4,
    int* __restrict__ csr, int N) {
    __shared__ int lcur[BSPAN];
    __shared__ int obase[BSPAN];
    int b = blockIdx.x, t = threadIdx.x;
    int v0 = b << BSHIFT;
    if (t < BSPAN) {
        int v = v0 + t;
        int o = (v < N) ? offsets4[v] : 0;
        lcur[t] = o;
        obase[t] = o;
    }
    __syncthreads();
    int p0 = bbase[b], p1 = p0 + btot[b];
    for (int i = p0 + t; i < p1; i += 256) {
        unsigned pk = pairs[i];
        int pos = atomicAdd(&lcur[pk >> 20], 1);
        csr[pos] = (int)(pk & 0xFFFFFu);
    }
    __syncthreads();
    if (t < BSPAN) {
        int v = v0 + t;
        if (v < N) {
            int e = lcur[t];  // == offsets4[v] + cnt[v]
            int e1 = obase[t] + ((e - obase[t] + 3) & ~3);
            for (; e < e1; ++e) csr[e] = N;  // pad -> zero feature row
        }
    }
}

// Fused GCN layer. 32-lane group per node. int4 src loads for gather ILP.
template <bool L1>
__global__ void __launch_bounds__(256) gcn_layer(
    const float* __restrict__ ht, const int* __restrict__ xi2,
    const float* __restrict__ ew, const float* __restrict__ dinvx,
    const int* __restrict__ offsets4, const int* __restrict__ cnt,
    const int* __restrict__ csr, const float* __restrict__ W,
    const float* __restrict__ bias, float* __restrict__ out,
    int N, int scale_next) {
    int c = threadIdx.x & 31;
    int grp = threadIdx.x >> 5;  // 0..7

    float w[CDIM];
    {
        const float4* Wrow = reinterpret_cast<const float4*>(W + c * CDIM);
        #pragma unroll
        for (int q = 0; q < CDIM / 4; ++q) {
            float4 t = Wrow[q];
            w[4 * q + 0] = t.x;
            w[4 * q + 1] = t.y;
            w[4 * q + 2] = t.z;
            w[4 * q + 3] = t.w;
        }
    }
    float bc = bias[c];

    for (int v0 = blockIdx.x * 8; v0 < N; v0 += gridDim.x * 8) {
        int v = v0 + grp;
        if (v >= N) continue;  // uniform across the 32-lane group
        float dv = dinvx[v];
        float acc;
        if (L1)
            acc = dv * ew[xi2[v] * CDIM + c];
        else
            acc = ht[v * CDIM + c];
        int e = offsets4[v];
        int e1 = e + ((cnt[v] + 3) & ~3);
        for (; e < e1; e += 4) {
            int4 s4 = *reinterpret_cast<const int4*>(&csr[e]);
            if (L1) {
                acc += dinvx[s4.x] * ew[xi2[s4.x] * CDIM + c];
                acc += dinvx[s4.y] * ew[xi2[s4.y] * CDIM + c];
                acc += dinvx[s4.z] * ew[xi2[s4.z] * CDIM + c];
                acc += dinvx[s4.w] * ew[xi2[s4.w] * CDIM + c];
            } else {
                float a0 = ht[s4.x * CDIM + c];
                float a1 = ht[s4.y * CDIM + c];
                float a2 = ht[s4.z * CDIM + c];
                float a3 = ht[s4.w * CDIM + c];
                acc += (a0 + a1) + (a2 + a3);
            }
        }
        float aggv = dv * acc;  // true aggregation value, channel c
        float o = bc;
        #pragma unroll
        for (int k = 0; k < CDIM; ++k)
            o = fmaf(__shfl(aggv, k, 32), w[k], o);
        o = fmaxf(o, 0.f);
        if (scale_next) o *= dv;
        out[v * CDIM + c] = o;
    }
}

// chunked segment-max over sorted batch; h >= 0 so uint-bit atomicMax is valid
#define PCHUNK 128
__global__ void pool_kernel(const float* __restrict__ h, const int* __restrict__ batch,
                            unsigned* __restrict__ pooled, int N) {
    __shared__ int sb[8 * PCHUNK];
    int t = threadIdx.x;
    int chunk0 = blockIdx.x * 8;
    int sbase = chunk0 * PCHUNK;
    for (int i = t; i < 8 * PCHUNK; i += 256)
        sb[i] = (sbase + i < N) ? batch[sbase + i] : -1;
    __syncthreads();
    int c = t & 31, cs = t >> 5;
    int i0 = (chunk0 + cs) * PCHUNK;
    if (i0 >= N) return;
    int curg = sb[cs * PCHUNK];
    float m = -1.0f;  // sentinel: nothing accumulated (h values are >= 0)
    for (int k = 0; k < PCHUNK; ++k) {
        int i = i0 + k;
        if (i >= N) break;
        int g = sb[cs * PCHUNK + k];
        float v = h[i * CDIM + c];
        if (g != curg) {
            if (m >= 0.f) atomicMax(&pooled[curg * CDIM + c], __float_as_uint(m));
            curg = g;
            m = v;
        } else {
            m = fmaxf(m, v);
        }
    }
    if (m >= 0.f && curg >= 0) atomicMax(&pooled[curg * CDIM + c], __float_as_uint(m));
}

// 32-lane group per graph; coalesced float4 weight rows + __shfl matmul.
__global__ void __launch_bounds__(256) head_kernel(
    const float* __restrict__ pooled,
    const float* __restrict__ d0_w, const float* __restrict__ d0_b,
    const float* __restrict__ dense_w, const float* __restrict__ dense_b,
    const float* __restrict__ fin_w, const float* __restrict__ fin_b,
    float* __restrict__ out, int G) {
    int c = threadIdx.x & 31;
    int grp = threadIdx.x >> 5;
    int g = blockIdx.x * 8 + grp;
    if (g >= G) return;

    float x = pooled[g * CDIM + c];  // lane c holds channel c

    const float* Ws[4] = {d0_w, dense_w, dense_w + CDIM * CDIM,
                          dense_w + 2 * CDIM * CDIM};
    const float* bs[4] = {d0_b, dense_b, dense_b + CDIM, dense_b + 2 * CDIM};
    for (int l = 0; l < 4; ++l) {
        float w[CDIM];
        const float4* Wrow = reinterpret_cast<const float4*>(Ws[l] + c * CDIM);
        #pragma unroll
        for (int q = 0; q < CDIM / 4; ++q) {
            float4 t = Wrow[q];
            w[4 * q + 0] = t.x;
            w[4 * q + 1] = t.y;
            w[4 * q + 2] = t.z;
            w[4 * q + 3] = t.w;
        }
        float acc = bs[l][c];
        #pragma unroll
        for (int k = 0; k < CDIM; ++k)
            acc = fmaf(__shfl(x, k, 32), w[k], acc);
        x = fmaxf(acc, 0.f);
    }
    // logits: butterfly reduce partial products across the 32-lane group
    float p0 = x * fin_w[c];
    float p1 = x * fin_w[CDIM + c];
    #pragma unroll
    for (int d = 16; d > 0; d >>= 1) {
        p0 += __shfl_xor(p0, d, 32);
        p1 += __shfl_xor(p1, d, 32);
    }
    float l0 = p0 + fin_b[0], l1 = p1 + fin_b[1];
    float mm = fmaxf(l0, l1);
    float lse = mm + logf(expf(l0 - mm) + expf(l1 - mm));
    if (c == 0) {
        out[g * 2 + 0] = l0 - lse;
        out[g * 2 + 1] = l1 - lse;
    }
}

extern "C" void kernel_launch(void* const* d_in, const int* in_sizes, int n_in,
                              void* d_out, int out_size, void* d_ws, size_t ws_size,
                              hipStream_t stream) {
    const int* x_idx = (const int*)d_in[0];
    const int* eidx = (const int*)d_in[1];
    const int* batch = (const int*)d_in[2];
    const float* embed_w = (const float*)d_in[3];
    const float* conv_w = (const float*)d_in[4];
    const float* conv_b = (const float*)d_in[5];
    const float* d0_w = (const float*)d_in[6];
    const float* d0_b = (const float*)d_in[7];
    const float* dense_w = (const float*)d_in[8];
    const float* dense_b = (const float*)d_in[9];
    const float* fin_w = (const float*)d_in[10];
    const float* fin_b = (const float*)d_in[11];

    int N = in_sizes[0];
    int E = in_sizes[1] / 2;
    int G = out_size / 2;
    const int* esrc = eidx;
    const int* edst = eidx + E;
    int nbuk = (N + BSPAN - 1) >> BSHIFT;  // 782

    char* ws = (char*)d_ws;
    size_t off = 0;
    auto take = [&](size_t bytes) -> char* {
        char* p = ws + off;
        off = (off + bytes + 255) & ~(size_t)255;
        return p;
    };
    int* cnt = (int*)take((size_t)N * 4);
    float* dinvx = (float*)take((size_t)(N + 1) * 4);
    int* xi2 = (int*)take((size_t)(N + 1) * 4);
    int* offsets4 = (int*)take((size_t)N * 4);
    int* bsums = (int*)take(4096 * 4);
    int* btot = (int*)take(MAXBUK * 4);
    int* bbase = (int*)take(MAXBUK * 4);
    int* gcursor = (int*)take(MAXBUK * 4);
    unsigned* pairs = (unsigned*)take((size_t)E * 4);
    int* csr = (int*)take((size_t)(E + 3 * N + 256) * 4);
    float* hA = (float*)take((size_t)(N + 1) * CDIM * 4);
    float* hB = (float*)take((size_t)(N + 1) * CDIM * 4);
    unsigned* pooled = (unsigned*)take((size_t)G * CDIM * 4);
    (void)ws_size;
    (void)n_in;

    hipMemsetAsync(btot, 0, MAXBUK * 4, stream);
    hipMemsetAsync(pooled, 0, (size_t)G * CDIM * 4, stream);
    hipMemsetAsync(hA + (size_t)N * CDIM, 0, CDIM * 4, stream);  // zero row N
    hipMemsetAsync(hB + (size_t)N * CDIM, 0, CDIM * 4, stream);

    int NB = (N + 255) / 256;
    int CB = (E + CHUNK - 1) / CHUNK;

    bucket_count<<<CB, 256, 0, stream>>>(edst, btot, E, nbuk);
    bscan_kernel<<<1, 1024, 0, stream>>>(btot, bbase, gcursor, nbuk);
    bin_kernel<<<CB, 256, 0, stream>>>(esrc, edst, gcursor, pairs, E, nbuk);
    node_count<<<nbuk, 256, 0, stream>>>(pairs, bbase, btot, x_idx, cnt, dinvx, xi2, N);
    scan_reduce<<<NB, 256, 0, stream>>>(cnt, bsums, N);
    scan_bsums<<<1, 512, 0, stream>>>(bsums, NB);
    scan_final<<<NB, 256, 0, stream>>>(cnt, bsums, offsets4, N);
    csr_scatter<<<nbuk, 256, 0, stream>>>(pairs, bbase, btot, offsets4, csr, N);

    int LB = 2048;  // grid-stride; amortizes per-block weight preload
    gcn_layer<true><<<LB, 256, 0, stream>>>(
        nullptr, xi2, embed_w, dinvx, offsets4, cnt, csr,
        conv_w + 0 * CDIM * CDIM, conv_b + 0 * CDIM, hA, N, 1);
    gcn_layer<false><<<LB, 256, 0, stream>>>(
        hA, nullptr, nullptr, dinvx, offsets4, cnt, csr,
        conv_w + 1 * CDIM * CDIM, conv_b + 1 * CDIM, hB, N, 1);
    gcn_layer<false><<<LB, 256, 0, stream>>>(
        hB, nullptr, nullptr, dinvx, offsets4, cnt, csr,
        conv_w + 2 * CDIM * CDIM, conv_b + 2 * CDIM, hA, N, 1);
    gcn_layer<false><<<LB, 256, 0, stream>>>(
        hA, nullptr, nullptr, dinvx, offsets4, cnt, csr,
        conv_w + 3 * CDIM * CDIM, conv_b + 3 * CDIM, hB, N, 1);
    gcn_layer<false><<<LB, 256, 0, stream>>>(
        hB, nullptr, nullptr, dinvx, offsets4, cnt, csr,
        conv_w + 4 * CDIM * CDIM, conv_b + 4 * CDIM, hA, N, 0);

    int nchunks = (N + PCHUNK - 1) / PCHUNK;
    pool_kernel<<<(nchunks + 7) / 8, 256, 0, stream>>>(hA, batch, pooled, N);
    head_kernel<<<(G + 7) / 8, 256, 0, stream>>>((const float*)pooled, d0_w, d0_b,
                                                 dense_w, dense_b, fin_w, fin_b,
                                                 (float*)d_out, G);
}